// Round 1
// baseline (28078.799 us; speedup 1.0000x reference)
//
#include <hip/hip_runtime.h>
#include <stdint.h>
#include <stddef.h>

#define NBATCH 32
#define NINPC  16
#define NSP    128
#define HW     16384      // NSP*NSP
#define CCH    128

typedef short bf16x8 __attribute__((ext_vector_type(8)));
typedef float f32x4  __attribute__((ext_vector_type(4)));

__device__ __forceinline__ float bf2f(unsigned short u){
    union { unsigned int i; float f; } v; v.i = ((unsigned int)u) << 16; return v.f;
}
__device__ __forceinline__ unsigned short f2bf(float f){
    union { float f; unsigned int i; } v; v.f = f;
    unsigned int x = v.i;
    x += 0x7fffu + ((x >> 16) & 1u);   // round-to-nearest-even
    return (unsigned short)(x >> 16);
}
__device__ __forceinline__ float u2f_lo(unsigned int u){ union{unsigned int i; float f;}v; v.i = u << 16;        return v.f; }
__device__ __forceinline__ float u2f_hi(unsigned int u){ union{unsigned int i; float f;}v; v.i = u & 0xffff0000u; return v.f; }

// ---------------------------------------------------------------- Msum = M[:,0]+M[:,1]
__global__ __launch_bounds__(256) void k_msum(const float* __restrict__ M, float* __restrict__ msum){
    int i = blockIdx.x*256 + threadIdx.x;           // over NBATCH*HW
    int b = i >> 14, hw = i & (HW-1);
    msum[i] = M[(size_t)b*2*HW + hw] + M[(size_t)b*2*HW + HW + hw];
}

// ---------------------------------------------------------------- conv a/b fused:
// A = relu((wa@x + ba)*Msum), B = relu((wb@x + bb)*Msum); x read once into registers.
template<int K, bool INBF>
__global__ __launch_bounds__(256) void k_conv_ab(
    const void* __restrict__ xin_,
    const float* __restrict__ wa, const float* __restrict__ ba,
    const float* __restrict__ wb, const float* __restrict__ bb,
    const float* __restrict__ msum,
    unsigned short* __restrict__ A, unsigned short* __restrict__ Bm, int b0)
{
    const int bi = blockIdx.y;
    const int bg = b0 + bi;
    const int hw = blockIdx.x*256 + threadIdx.x;
    float xv[K];
    if constexpr (INBF) {
        const unsigned short* xp = (const unsigned short*)xin_ + (size_t)bi*K*HW + hw;
        #pragma unroll
        for(int c=0;c<K;c++) xv[c] = bf2f(xp[(size_t)c*HW]);
    } else {
        const float* xp = (const float*)xin_ + (size_t)bg*K*HW + hw;
        #pragma unroll
        for(int c=0;c<K;c++) xv[c] = xp[(size_t)c*HW];
    }
    const float ms = msum[(size_t)bg*HW + hw];
    unsigned short* Ap = A  + (size_t)bi*CCH*HW + hw;
    unsigned short* Bp = Bm + (size_t)bi*CCH*HW + hw;
    #pragma unroll 1
    for(int o=0;o<CCH;o++){
        float aA = ba[o], aB = bb[o];
        const float* wra = wa + o*K;
        const float* wrb = wb + o*K;
        #pragma unroll
        for(int c=0;c<K;c++){ aA += wra[c]*xv[c]; aB += wrb[c]*xv[c]; }
        aA *= ms; aB *= ms;
        aA = aA > 0.f ? aA : 0.f;
        aB = aB > 0.f ? aB : 0.f;
        Ap[(size_t)o*HW] = f2bf(aA);
        Bp[(size_t)o*HW] = f2bf(aB);
    }
}

// ---------------------------------------------------------------- batched spatial matmul:
// P[b,c] = (A[b,c] @ B[b,c]) * Msum[b]   (128x128x128, bf16 MFMA, fp32 accum)
__global__ __launch_bounds__(256) void k_bmm(
    const unsigned short* __restrict__ A, const unsigned short* __restrict__ Bm,
    const float* __restrict__ msum, unsigned short* __restrict__ P, int b0)
{
    __shared__ unsigned short Bs[128*136];          // B^T, row stride 136 (16B aligned)
    const int m  = blockIdx.x;                      // bi*CCH + c
    const int bi = m >> 7;
    const int bg = b0 + bi;
    const unsigned short* Ab = A  + (size_t)m*HW;
    const unsigned short* Bb = Bm + (size_t)m*HW;
    unsigned short*       Pb = P  + (size_t)m*HW;
    const float* ms = msum + (size_t)bg*HW;
    const int t = threadIdx.x;

    // stage B transposed: Bs[j][k] = B[k][j]
    #pragma unroll
    for(int it=0; it<8; it++){
        int task = it*256 + t;
        int j  = task & 127;
        int kg = task >> 7;                         // 0..15, k = kg*8..kg*8+7
        unsigned short v[8];
        #pragma unroll
        for(int i=0;i<8;i++) v[i] = Bb[(size_t)(kg*8+i)*128 + j];
        uint4 pk;
        pk.x = (unsigned int)v[0] | ((unsigned int)v[1]<<16);
        pk.y = (unsigned int)v[2] | ((unsigned int)v[3]<<16);
        pk.z = (unsigned int)v[4] | ((unsigned int)v[5]<<16);
        pk.w = (unsigned int)v[6] | ((unsigned int)v[7]<<16);
        *reinterpret_cast<uint4*>(&Bs[j*136 + kg*8]) = pk;
    }
    __syncthreads();

    const int w  = t >> 6;                          // wave 0..3 -> rows [32w,32w+32)
    const int l  = t & 63;
    const int lr = l & 15;
    const int lg = l >> 4;                          // 0..3
    f32x4 acc[2][8];
    #pragma unroll
    for(int rt=0;rt<2;rt++)
        #pragma unroll
        for(int ct=0;ct<8;ct++) acc[rt][ct] = (f32x4){0.f,0.f,0.f,0.f};

    #pragma unroll 1
    for(int kk=0;kk<4;kk++){
        bf16x8 af[2];
        #pragma unroll
        for(int rt=0;rt<2;rt++){
            int row = w*32 + rt*16 + lr;
            af[rt] = *reinterpret_cast<const bf16x8*>(Ab + (size_t)row*128 + kk*32 + lg*8);
        }
        #pragma unroll
        for(int ct=0;ct<8;ct++){
            bf16x8 bfr = *reinterpret_cast<const bf16x8*>(&Bs[(ct*16+lr)*136 + kk*32 + lg*8]);
            acc[0][ct] = __builtin_amdgcn_mfma_f32_16x16x32_bf16(af[0], bfr, acc[0][ct], 0,0,0);
            acc[1][ct] = __builtin_amdgcn_mfma_f32_16x16x32_bf16(af[1], bfr, acc[1][ct], 0,0,0);
        }
    }
    // C/D layout: col = lane&15, row = (lane>>4)*4 + reg   [m89-verified]
    #pragma unroll
    for(int rt=0;rt<2;rt++){
        #pragma unroll
        for(int ct=0;ct<8;ct++){
            #pragma unroll
            for(int r=0;r<4;r++){
                int row = w*32 + rt*16 + lg*4 + r;
                int col = ct*16 + lr;
                float v = acc[rt][ct][r] * ms[row*128 + col];
                Pb[(size_t)row*128 + col] = f2bf(v);
            }
        }
    }
}

// ---------------------------------------------------------------- conv c (concat(P,x)):
// Xout = relu((wc @ [P; x] + bc)*Msum)
template<int CX, bool XBF>
__global__ __launch_bounds__(256) void k_conv_c(
    const unsigned short* __restrict__ P, const void* __restrict__ xin_,
    const float* __restrict__ wc, const float* __restrict__ bcv,
    const float* __restrict__ msum, unsigned short* __restrict__ Xout, int b0)
{
    constexpr int KTOT = CCH + CX;
    const int bi = blockIdx.y;
    const int bg = b0 + bi;
    const int hw = blockIdx.x*256 + threadIdx.x;

    unsigned int pv[64];                            // 128 P-channels, bf16 packed
    const unsigned short* Pp = P + (size_t)bi*CCH*HW + hw;
    #pragma unroll
    for(int c2=0;c2<64;c2++)
        pv[c2] = (unsigned int)Pp[(size_t)(2*c2)*HW] | ((unsigned int)Pp[(size_t)(2*c2+1)*HW] << 16);

    unsigned int xvb[XBF ? CX/2 : 1];
    float        xvf[XBF ? 1 : CX];
    if constexpr (XBF){
        const unsigned short* Xp = (const unsigned short*)xin_ + (size_t)bi*CX*HW + hw;
        #pragma unroll
        for(int c2=0;c2<CX/2;c2++)
            xvb[c2] = (unsigned int)Xp[(size_t)(2*c2)*HW] | ((unsigned int)Xp[(size_t)(2*c2+1)*HW] << 16);
    } else {
        const float* Xp = (const float*)xin_ + (size_t)bg*CX*HW + hw;
        #pragma unroll
        for(int c=0;c<CX;c++) xvf[c] = Xp[(size_t)c*HW];
    }
    const float ms = msum[(size_t)bg*HW + hw];
    unsigned short* Op = Xout + (size_t)bi*CCH*HW + hw;

    #pragma unroll 1
    for(int ot=0; ot<16; ot++){
        float acc[8];
        #pragma unroll
        for(int i=0;i<8;i++) acc[i] = bcv[ot*8+i];
        #pragma unroll
        for(int c2=0;c2<64;c2++){
            float lo = u2f_lo(pv[c2]);
            float hi = u2f_hi(pv[c2]);
            #pragma unroll
            for(int i=0;i<8;i++){
                const float* wr = wc + (ot*8+i)*KTOT;
                acc[i] += wr[2*c2]*lo + wr[2*c2+1]*hi;
            }
        }
        if constexpr (XBF){
            #pragma unroll
            for(int c2=0;c2<CX/2;c2++){
                float lo = u2f_lo(xvb[c2]);
                float hi = u2f_hi(xvb[c2]);
                #pragma unroll
                for(int i=0;i<8;i++){
                    const float* wr = wc + (ot*8+i)*KTOT + CCH;
                    acc[i] += wr[2*c2]*lo + wr[2*c2+1]*hi;
                }
            }
        } else {
            #pragma unroll
            for(int c=0;c<CX;c++){
                #pragma unroll
                for(int i=0;i<8;i++)
                    acc[i] += wc[(ot*8+i)*KTOT + CCH + c]*xvf[c];
            }
        }
        #pragma unroll
        for(int i=0;i<8;i++){
            float v = acc[i]*ms; v = v > 0.f ? v : 0.f;
            Op[(size_t)(ot*8+i)*HW] = f2bf(v);
        }
    }
}

// ---------------------------------------------------------------- xo[bg, off+c] = sum_hw x*Mdiag
__global__ __launch_bounds__(256) void k_reduce(
    const unsigned short* __restrict__ X, const float* __restrict__ M,
    float* __restrict__ xo, int b0, int off)
{
    const int m = blockIdx.x;                        // bi*CCH + c
    const int bi = m >> 7, c = m & 127;
    const int bg = b0 + bi;
    const unsigned short* Xp = X + (size_t)m*HW;
    const float* Md = M + (size_t)bg*2*HW;           // M[:,0] = diag mask
    float s = 0.f;
    for(int i=threadIdx.x; i<HW; i+=256) s += bf2f(Xp[i]) * Md[i];
    __shared__ float red[256];
    red[threadIdx.x] = s; __syncthreads();
    for(int st=128; st>0; st>>=1){
        if(threadIdx.x < st) red[threadIdx.x] += red[threadIdx.x+st];
        __syncthreads();
    }
    if(threadIdx.x == 0) xo[(size_t)bg*384 + off + c] = red[0];
}

// ---------------------------------------------------------------- head
__global__ __launch_bounds__(1024) void k_head(
    const float* __restrict__ xo, const float* __restrict__ h1w, const float* __restrict__ h1b,
    const float* __restrict__ h2w, const float* __restrict__ h2b, float* __restrict__ out)
{
    __shared__ float hbuf[NBATCH][32];
    const int t = threadIdx.x;
    const int b = t >> 5, j = t & 31;
    float a = h1b[j];
    #pragma unroll 8
    for(int k=0;k<384;k++) a += xo[b*384+k]*h1w[j*384+k];
    a = a > 0.f ? a : 0.f;
    hbuf[b][j] = a;
    __syncthreads();
    if(j == 0){
        float s = h2b[0];
        #pragma unroll
        for(int k=0;k<32;k++) s += hbuf[b][k]*h2w[k];
        out[b] = s;
    }
}

// ----------------------------------------------------------------
extern "C" void kernel_launch(void* const* d_in, const int* in_sizes, int n_in,
                              void* d_out, int out_size, void* d_ws, size_t ws_size,
                              hipStream_t stream)
{
    (void)in_sizes; (void)n_in; (void)out_size;
    const float* X2  = (const float*)d_in[0];
    const float* M   = (const float*)d_in[1];
    const float* w11 = (const float*)d_in[2];  const float* b11 = (const float*)d_in[3];
    const float* w12 = (const float*)d_in[4];  const float* b12 = (const float*)d_in[5];
    const float* w13 = (const float*)d_in[6];  const float* b13 = (const float*)d_in[7];
    const float* w21 = (const float*)d_in[8];  const float* b21 = (const float*)d_in[9];
    const float* w22 = (const float*)d_in[10]; const float* b22 = (const float*)d_in[11];
    const float* w23 = (const float*)d_in[12]; const float* b23 = (const float*)d_in[13];
    const float* w31 = (const float*)d_in[14]; const float* b31 = (const float*)d_in[15];
    const float* w32 = (const float*)d_in[16]; const float* b32 = (const float*)d_in[17];
    const float* w33 = (const float*)d_in[18]; const float* b33 = (const float*)d_in[19];
    const float* h1w = (const float*)d_in[20]; const float* h1b = (const float*)d_in[21];
    const float* h2w = (const float*)d_in[22]; const float* h2b = (const float*)d_in[23];
    float* out = (float*)d_out;

    char* ws = (char*)d_ws;
    size_t off = 0;
    float* msum = (float*)(ws + off); off += (size_t)NBATCH*HW*4;          // 2 MB
    float* xo   = (float*)(ws + off); off += (size_t)NBATCH*384*4;         // 48 KB
    off = (off + 255) & ~(size_t)255;

    // pick batch-chunk size so 4 bf16 buffers fit in workspace
    int bc = 32;
    while (bc > 1 && off + 4ull*(size_t)bc*CCH*HW*2 > ws_size) bc >>= 1;
    size_t bufb = (size_t)bc*CCH*HW*2;
    unsigned short* bufA = (unsigned short*)(ws + off);
    unsigned short* bufB = (unsigned short*)(ws + off + bufb);
    unsigned short* bufP = (unsigned short*)(ws + off + 2*bufb);
    unsigned short* bufX = (unsigned short*)(ws + off + 3*bufb);

    k_msum<<<(NBATCH*HW)/256, 256, 0, stream>>>(M, msum);
    hipMemsetAsync(xo, 0, (size_t)NBATCH*384*4, stream);

    for(int b0 = 0; b0 < NBATCH; b0 += bc){
        dim3 gconv(HW/256, bc);
        dim3 gmat(bc*CCH);
        // ---- block 1 (x = X2, 16 ch)
        k_conv_ab<NINPC,false><<<gconv, 256, 0, stream>>>(X2, w11,b11, w12,b12, msum, bufA, bufB, b0);
        k_bmm<<<gmat, 256, 0, stream>>>(bufA, bufB, msum, bufP, b0);
        k_conv_c<NINPC,false><<<gconv, 256, 0, stream>>>(bufP, X2, w13, b13, msum, bufX, b0);
        k_reduce<<<gmat, 256, 0, stream>>>(bufX, M, xo, b0, 0);
        // ---- block 2 (x = bufX)
        k_conv_ab<CCH,true><<<gconv, 256, 0, stream>>>(bufX, w21,b21, w22,b22, msum, bufA, bufB, b0);
        k_bmm<<<gmat, 256, 0, stream>>>(bufA, bufB, msum, bufP, b0);
        k_conv_c<CCH,true><<<gconv, 256, 0, stream>>>(bufP, bufX, w23, b23, msum, bufA, b0);
        k_reduce<<<gmat, 256, 0, stream>>>(bufA, M, xo, b0, 128);
        // ---- block 3 (x = bufA)
        k_conv_ab<CCH,true><<<gconv, 256, 0, stream>>>(bufA, w31,b31, w32,b32, msum, bufB, bufP, b0);
        k_bmm<<<gmat, 256, 0, stream>>>(bufB, bufP, msum, bufX, b0);
        k_conv_c<CCH,true><<<gconv, 256, 0, stream>>>(bufX, bufA, w33, b33, msum, bufB, b0);
        k_reduce<<<gmat, 256, 0, stream>>>(bufB, M, xo, b0, 256);
    }
    k_head<<<1, 1024, 0, stream>>>(xo, h1w, h1b, h2w, h2b, out);
}

// Round 3
// 1412.682 us; speedup vs baseline: 19.8762x; 19.8762x over previous
//
#include <hip/hip_runtime.h>
#include <stdint.h>
#include <stddef.h>

#define NBATCH 32
#define HW     16384      // 128*128
#define CCH    128

typedef short bf16x8 __attribute__((ext_vector_type(8)));
typedef float f32x4  __attribute__((ext_vector_type(4)));

__device__ __forceinline__ float bf2f(unsigned short u){
    union { unsigned int i; float f; } v; v.i = ((unsigned int)u) << 16; return v.f;
}
__device__ __forceinline__ unsigned short f2bf(float f){
    union { float f; unsigned int i; } v; v.f = f;
    unsigned int x = v.i;
    x += 0x7fffu + ((x >> 16) & 1u);   // round-to-nearest-even
    return (unsigned short)(x >> 16);
}

// ---------------------------------------------------------------- weight prep (hi/lo split):
// layout per conv: [NCH][2][M][32] bf16, half0=hi, half1=lo, K zero/dup-padded.
// segment offsets (shorts):
//   Wab1 @0       [1][2][256][32]  (K=16; slots 0-15 = W, slots 16-31 = W duplicated -> pairs X2hi/X2lo)
//   Wc1  @16384   [5][2][128][32]  (w13, K=160: ck<4 -> P cols; ck=4 dup cols 128..143)
//   Wab2 @57344   [4][2][256][32]  (w21/w22)
//   Wc2  @122880  [8][2][128][32]  (w23)
//   Wab3 @188416  [4][2][256][32]  (w31/w32)
//   Wc3  @253952  [8][2][128][32]  (w33)   total 319488 shorts
#define WPREP_TOTAL 319488
__global__ __launch_bounds__(256) void k_prep(
    const float* __restrict__ w11, const float* __restrict__ w12, const float* __restrict__ w13,
    const float* __restrict__ w21, const float* __restrict__ w22, const float* __restrict__ w23,
    const float* __restrict__ w31, const float* __restrict__ w32, const float* __restrict__ w33,
    unsigned short* __restrict__ wp)
{
    int i = blockIdx.x*256 + threadIdx.x;
    if(i >= WPREP_TOTAL) return;
    float v; int half;
    if(i < 16384){
        int j = i; half = (j >> 13) & 1;
        int r = (j >> 5) & 255, c = j & 31, col = c & 15;
        v = (r < 128) ? w11[r*16 + col] : w12[(r-128)*16 + col];
    } else if(i < 57344){
        int j = i - 16384; int ck = j >> 13; int jj = j & 8191;
        half = jj >> 12;
        int r = (jj >> 5) & 127, c = jj & 31;
        int col = (ck < 4) ? (ck*32 + c) : (128 + (c & 15));
        v = w13[r*144 + col];
    } else if(i < 122880){
        int j = i - 57344; int ck = j >> 14; int jj = j & 16383;
        half = jj >> 13;
        int r = (jj >> 5) & 255, c = jj & 31, col = ck*32 + c;
        v = (r < 128) ? w21[r*128 + col] : w22[(r-128)*128 + col];
    } else if(i < 188416){
        int j = i - 122880; int ck = j >> 13; int jj = j & 8191;
        half = jj >> 12;
        int r = (jj >> 5) & 127, c = jj & 31, col = ck*32 + c;
        v = w23[r*256 + col];
    } else if(i < 253952){
        int j = i - 188416; int ck = j >> 14; int jj = j & 16383;
        half = jj >> 13;
        int r = (jj >> 5) & 255, c = jj & 31, col = ck*32 + c;
        v = (r < 128) ? w31[r*128 + col] : w32[(r-128)*128 + col];
    } else {
        int j = i - 253952; int ck = j >> 13; int jj = j & 8191;
        half = jj >> 12;
        int r = (jj >> 5) & 127, c = jj & 31, col = ck*32 + c;
        v = w33[r*256 + col];
    }
    unsigned short hi = f2bf(v);
    wp[i] = half ? f2bf(v - bf2f(hi)) : hi;
}

// ---------------------------------------------------------------- X2 hi/lo split:
// X2b[b][32][HW]: channels 0-15 = bf16(X2), 16-31 = bf16(X2 - hi)
__global__ __launch_bounds__(256) void k_xprep(const float* __restrict__ X2, unsigned short* __restrict__ X2b){
    int i = blockIdx.x*256 + threadIdx.x;        // over 32*16*HW
    int hw = i & (HW-1);
    int rest = i >> 14;
    int c = rest & 15, b = rest >> 4;
    float v = X2[i];
    unsigned short hi = f2bf(v);
    size_t dst = (size_t)b*32*HW + (size_t)c*HW + hw;
    X2b[dst] = hi;
    X2b[dst + (size_t)16*HW] = f2bf(v - bf2f(hi));
}

// ---------------------------------------------------------------- Msum = M[:,0]+M[:,1]
__global__ __launch_bounds__(256) void k_msum(const float* __restrict__ M, float* __restrict__ msum){
    int i = blockIdx.x*256 + threadIdx.x;
    int b = i >> 14, hw = i & (HW-1);
    msum[i] = M[(size_t)b*2*HW + hw] + M[(size_t)b*2*HW + HW + hw];
}

// ---------------------------------------------------------------- fused conv a+b (MFMA GEMM, split-W)
// Out[256][hw]: rows<128 -> A=relu((wa x + ba)ms), rows>=128 -> B. M=256, Ntile=128, KC=32 x 2 MFMA.
template<int NCH, int CIN, bool GX>
__global__ __launch_bounds__(256,2) void k_cab(
    const unsigned short* __restrict__ Wp,   // [NCH][2][256][32] bf16
    const unsigned short* __restrict__ xin,  // bf16 [b][CIN][HW], b = GX? bg : bi
    const float* __restrict__ ba, const float* __restrict__ bb,
    const float* __restrict__ msum,
    unsigned short* __restrict__ A, unsigned short* __restrict__ Bm, int b0)
{
    __shared__ unsigned short Wlh[256*40];
    __shared__ unsigned short Wll[256*40];
    __shared__ unsigned short Xt[128*40];
    const int bi = blockIdx.y, bg = b0 + bi;
    const int hw0 = blockIdx.x * 128;
    const int t = threadIdx.x;
    const int w = t >> 6, l = t & 63;
    const int lr = l & 15, lg = l >> 4;
    const unsigned short* xbase = xin + (size_t)(GX ? bg : bi)*CIN*HW;

    f32x4 acc[4][8];
    #pragma unroll
    for(int mf=0; mf<4; mf++)
        #pragma unroll
        for(int nf=0; nf<8; nf++) acc[mf][nf] = (f32x4){0.f,0.f,0.f,0.f};

    for(int ck=0; ck<NCH; ck++){
        if(ck) __syncthreads();
        // ---- stage W chunk [2][256][32] -> Wlh/Wll [256][40]
        #pragma unroll
        for(int it=0; it<8; it++){
            int idx = it*256 + t;
            int h = idx >> 10;                      // constant per it
            int r = (idx >> 2) & 255, jg = (idx & 3) * 8;
            uint4 val = *reinterpret_cast<const uint4*>(Wp + (size_t)ck*16384 + h*8192 + r*32 + jg);
            unsigned short* dl = h ? Wll : Wlh;
            *reinterpret_cast<uint4*>(&dl[r*40 + jg]) = val;
        }
        // ---- stage X chunk transposed -> Xt[hw][c]
        #pragma unroll
        for(int it=0; it<2; it++){
            int hw = t & 127;
            int c0 = (it*2 + (t >> 7)) * 8;
            const unsigned short* xs = xbase + (size_t)(ck*32 + c0)*HW + hw0 + hw;
            unsigned short v[8];
            #pragma unroll
            for(int i=0;i<8;i++) v[i] = xs[(size_t)i*HW];
            uint4 pk;
            pk.x = (unsigned int)v[0] | ((unsigned int)v[1] << 16);
            pk.y = (unsigned int)v[2] | ((unsigned int)v[3] << 16);
            pk.z = (unsigned int)v[4] | ((unsigned int)v[5] << 16);
            pk.w = (unsigned int)v[6] | ((unsigned int)v[7] << 16);
            *reinterpret_cast<uint4*>(&Xt[hw*40 + c0]) = pk;
        }
        __syncthreads();
        // ---- compute: wave w owns out rows [w*64, w*64+64)
        bf16x8 ah[4], al[4];
        #pragma unroll
        for(int mf=0; mf<4; mf++){
            ah[mf] = *reinterpret_cast<const bf16x8*>(&Wlh[(w*64 + mf*16 + lr)*40 + lg*8]);
            al[mf] = *reinterpret_cast<const bf16x8*>(&Wll[(w*64 + mf*16 + lr)*40 + lg*8]);
        }
        #pragma unroll
        for(int nf=0; nf<8; nf++){
            bf16x8 bfr = *reinterpret_cast<const bf16x8*>(&Xt[(nf*16 + lr)*40 + lg*8]);
            #pragma unroll
            for(int mf=0; mf<4; mf++){
                acc[mf][nf] = __builtin_amdgcn_mfma_f32_16x16x32_bf16(ah[mf], bfr, acc[mf][nf], 0,0,0);
                acc[mf][nf] = __builtin_amdgcn_mfma_f32_16x16x32_bf16(al[mf], bfr, acc[mf][nf], 0,0,0);
            }
        }
    }
    // ---- epilogue: bias, *Msum, relu, bf16 store
    float msv[8];
    #pragma unroll
    for(int nf=0; nf<8; nf++) msv[nf] = msum[(size_t)bg*HW + hw0 + nf*16 + lr];
    const float* bsel = (w < 2) ? ba : bb;
    unsigned short* dst = ((w < 2) ? A : Bm) + (size_t)bi*CCH*HW;
    const int rbase = (w & 1) * 64;
    #pragma unroll
    for(int mf=0; mf<4; mf++){
        #pragma unroll
        for(int reg=0; reg<4; reg++){
            int rl = rbase + mf*16 + lg*4 + reg;
            float bv = bsel[rl];
            #pragma unroll
            for(int nf=0; nf<8; nf++){
                float v2 = (acc[mf][nf][reg] + bv) * msv[nf];
                v2 = v2 > 0.f ? v2 : 0.f;
                dst[(size_t)rl*HW + hw0 + nf*16 + lr] = f2bf(v2);
            }
        }
    }
}

// ---------------------------------------------------------------- conv c (concat GEMM, split-W) + fused diag-reduce
// Out[128][hw] = relu((wc [P;x] + bc)ms); xo[bg,off+o] += sum_hw Out*Mdiag. M=128, Ntile=256.
template<int NCHP, int NCHX, int CINX, bool GX>
__global__ __launch_bounds__(256,2) void k_cc(
    const unsigned short* __restrict__ Wp,   // [NCHP+NCHX][2][128][32] bf16
    const unsigned short* __restrict__ P,    // bf16 [bi][128][HW]
    const unsigned short* __restrict__ x2,   // bf16 [b][CINX][HW], b = GX? bg : bi
    const float* __restrict__ bc,
    const float* __restrict__ msum, const float* __restrict__ M,
    unsigned short* __restrict__ Xout, float* __restrict__ xo,
    int b0, int xo_off)
{
    constexpr int NCH = NCHP + NCHX;
    __shared__ unsigned short Wlh[128*40];
    __shared__ unsigned short Wll[128*40];
    __shared__ unsigned short Xt[256*40];
    const int bi = blockIdx.y, bg = b0 + bi;
    const int hw0 = blockIdx.x * 256;
    const int t = threadIdx.x;
    const int w = t >> 6, l = t & 63;
    const int lr = l & 15, lg = l >> 4;
    const unsigned short* pbase = P  + (size_t)bi*CCH*HW;
    const unsigned short* xbase = x2 + (size_t)(GX ? bg : bi)*CINX*HW;

    f32x4 acc[8][4];
    #pragma unroll
    for(int mf=0; mf<8; mf++)
        #pragma unroll
        for(int nf=0; nf<4; nf++) acc[mf][nf] = (f32x4){0.f,0.f,0.f,0.f};

    for(int ck=0; ck<NCH; ck++){
        if(ck) __syncthreads();
        // ---- stage W chunk [2][128][32] -> Wlh/Wll [128][40]
        #pragma unroll
        for(int it=0; it<4; it++){
            int idx = it*256 + t;
            int h = idx >> 9;                       // constant per it
            int r = (idx >> 2) & 127, jg = (idx & 3) * 8;
            uint4 val = *reinterpret_cast<const uint4*>(Wp + (size_t)ck*8192 + h*4096 + r*32 + jg);
            unsigned short* dl = h ? Wll : Wlh;
            *reinterpret_cast<uint4*>(&dl[r*40 + jg]) = val;
        }
        // ---- stage X chunk transposed: ck<NCHP from P else from x2
        #pragma unroll
        for(int it=0; it<4; it++){
            int hw = t;
            int c0 = it * 8;
            const unsigned short* xs = (ck < NCHP)
                ? (pbase + (size_t)(ck*32 + c0)*HW + hw0 + hw)
                : (xbase + (size_t)((ck-NCHP)*32 + c0)*HW + hw0 + hw);
            unsigned short v[8];
            #pragma unroll
            for(int i=0;i<8;i++) v[i] = xs[(size_t)i*HW];
            uint4 pk;
            pk.x = (unsigned int)v[0] | ((unsigned int)v[1] << 16);
            pk.y = (unsigned int)v[2] | ((unsigned int)v[3] << 16);
            pk.z = (unsigned int)v[4] | ((unsigned int)v[5] << 16);
            pk.w = (unsigned int)v[6] | ((unsigned int)v[7] << 16);
            *reinterpret_cast<uint4*>(&Xt[hw*40 + c0]) = pk;
        }
        __syncthreads();
        // ---- compute: wave w owns cols [w*64, w*64+64)
        bf16x8 bfr[4];
        #pragma unroll
        for(int nf=0; nf<4; nf++)
            bfr[nf] = *reinterpret_cast<const bf16x8*>(&Xt[(w*64 + nf*16 + lr)*40 + lg*8]);
        #pragma unroll
        for(int mf=0; mf<8; mf++){
            bf16x8 ah = *reinterpret_cast<const bf16x8*>(&Wlh[(mf*16 + lr)*40 + lg*8]);
            bf16x8 al = *reinterpret_cast<const bf16x8*>(&Wll[(mf*16 + lr)*40 + lg*8]);
            #pragma unroll
            for(int nf=0; nf<4; nf++){
                acc[mf][nf] = __builtin_amdgcn_mfma_f32_16x16x32_bf16(ah, bfr[nf], acc[mf][nf], 0,0,0);
                acc[mf][nf] = __builtin_amdgcn_mfma_f32_16x16x32_bf16(al, bfr[nf], acc[mf][nf], 0,0,0);
            }
        }
    }
    // ---- epilogue: bias, *Msum, relu, store; fused xo += sum(out * Mdiag)
    float msv[4], mdv[4];
    #pragma unroll
    for(int nf=0; nf<4; nf++){
        int hwi = hw0 + w*64 + nf*16 + lr;
        msv[nf] = msum[(size_t)bg*HW + hwi];
        mdv[nf] = M[(size_t)bg*2*HW + hwi];
    }
    unsigned short* dst = Xout + (size_t)bi*CCH*HW;
    #pragma unroll
    for(int mf=0; mf<8; mf++){
        float red[4] = {0.f,0.f,0.f,0.f};
        #pragma unroll
        for(int reg=0; reg<4; reg++){
            int row = mf*16 + lg*4 + reg;
            float bv = bc[row];
            #pragma unroll
            for(int nf=0; nf<4; nf++){
                float v2 = (acc[mf][nf][reg] + bv) * msv[nf];
                v2 = v2 > 0.f ? v2 : 0.f;
                dst[(size_t)row*HW + hw0 + w*64 + nf*16 + lr] = f2bf(v2);
                red[reg] += v2 * mdv[nf];
            }
        }
        #pragma unroll
        for(int reg=0; reg<4; reg++){
            float r = red[reg];
            r += __shfl_xor(r, 1);
            r += __shfl_xor(r, 2);
            r += __shfl_xor(r, 4);
            r += __shfl_xor(r, 8);
            if(lr == 0)
                atomicAdd(&xo[(size_t)bg*384 + xo_off + mf*16 + lg*4 + reg], r);
        }
    }
}

// ---------------------------------------------------------------- batched spatial matmul:
// P[b,c] = (A[b,c] @ B[b,c]) * Msum[b]   (128x128x128, bf16 MFMA, fp32 accum)
__global__ __launch_bounds__(256) void k_bmm(
    const unsigned short* __restrict__ A, const unsigned short* __restrict__ Bm,
    const float* __restrict__ msum, unsigned short* __restrict__ P, int b0)
{
    __shared__ unsigned short Bs[128*136];
    const int m  = blockIdx.x;
    const int bi = m >> 7;
    const int bg = b0 + bi;
    const unsigned short* Ab = A  + (size_t)m*HW;
    const unsigned short* Bb = Bm + (size_t)m*HW;
    unsigned short*       Pb = P  + (size_t)m*HW;
    const float* ms = msum + (size_t)bg*HW;
    const int t = threadIdx.x;

    #pragma unroll
    for(int it=0; it<8; it++){
        int task = it*256 + t;
        int j  = task & 127;
        int kg = task >> 7;
        unsigned short v[8];
        #pragma unroll
        for(int i=0;i<8;i++) v[i] = Bb[(size_t)(kg*8+i)*128 + j];
        uint4 pk;
        pk.x = (unsigned int)v[0] | ((unsigned int)v[1]<<16);
        pk.y = (unsigned int)v[2] | ((unsigned int)v[3]<<16);
        pk.z = (unsigned int)v[4] | ((unsigned int)v[5]<<16);
        pk.w = (unsigned int)v[6] | ((unsigned int)v[7]<<16);
        *reinterpret_cast<uint4*>(&Bs[j*136 + kg*8]) = pk;
    }
    __syncthreads();

    const int w  = t >> 6;
    const int l  = t & 63;
    const int lr = l & 15;
    const int lg = l >> 4;
    f32x4 acc[2][8];
    #pragma unroll
    for(int rt=0;rt<2;rt++)
        #pragma unroll
        for(int ct=0;ct<8;ct++) acc[rt][ct] = (f32x4){0.f,0.f,0.f,0.f};

    #pragma unroll 1
    for(int kk=0;kk<4;kk++){
        bf16x8 af[2];
        #pragma unroll
        for(int rt=0;rt<2;rt++){
            int row = w*32 + rt*16 + lr;
            af[rt] = *reinterpret_cast<const bf16x8*>(Ab + (size_t)row*128 + kk*32 + lg*8);
        }
        #pragma unroll
        for(int ct=0;ct<8;ct++){
            bf16x8 bfr = *reinterpret_cast<const bf16x8*>(&Bs[(ct*16+lr)*136 + kk*32 + lg*8]);
            acc[0][ct] = __builtin_amdgcn_mfma_f32_16x16x32_bf16(af[0], bfr, acc[0][ct], 0,0,0);
            acc[1][ct] = __builtin_amdgcn_mfma_f32_16x16x32_bf16(af[1], bfr, acc[1][ct], 0,0,0);
        }
    }
    #pragma unroll
    for(int rt=0;rt<2;rt++){
        #pragma unroll
        for(int ct=0;ct<8;ct++){
            #pragma unroll
            for(int r=0;r<4;r++){
                int row = w*32 + rt*16 + lg*4 + r;
                int col = ct*16 + lr;
                float v = acc[rt][ct][r] * ms[row*128 + col];
                Pb[(size_t)row*128 + col] = f2bf(v);
            }
        }
    }
}

// ---------------------------------------------------------------- head
__global__ __launch_bounds__(1024) void k_head(
    const float* __restrict__ xo, const float* __restrict__ h1w, const float* __restrict__ h1b,
    const float* __restrict__ h2w, const float* __restrict__ h2b, float* __restrict__ out)
{
    __shared__ float hbuf[NBATCH][32];
    const int t = threadIdx.x;
    const int b = t >> 5, j = t & 31;
    float a = h1b[j];
    #pragma unroll 8
    for(int k=0;k<384;k++) a += xo[b*384+k]*h1w[j*384+k];
    a = a > 0.f ? a : 0.f;
    hbuf[b][j] = a;
    __syncthreads();
    if(j == 0){
        float s = h2b[0];
        #pragma unroll
        for(int k=0;k<32;k++) s += hbuf[b][k]*h2w[k];
        out[b] = s;
    }
}

// ----------------------------------------------------------------
extern "C" void kernel_launch(void* const* d_in, const int* in_sizes, int n_in,
                              void* d_out, int out_size, void* d_ws, size_t ws_size,
                              hipStream_t stream)
{
    (void)in_sizes; (void)n_in; (void)out_size;
    const float* X2  = (const float*)d_in[0];
    const float* M   = (const float*)d_in[1];
    const float* w11 = (const float*)d_in[2];  const float* b11 = (const float*)d_in[3];
    const float* w12 = (const float*)d_in[4];  const float* b12 = (const float*)d_in[5];
    const float* w13 = (const float*)d_in[6];  const float* b13 = (const float*)d_in[7];
    const float* w21 = (const float*)d_in[8];  const float* b21 = (const float*)d_in[9];
    const float* w22 = (const float*)d_in[10]; const float* b22 = (const float*)d_in[11];
    const float* w23 = (const float*)d_in[12]; const float* b23 = (const float*)d_in[13];
    const float* w31 = (const float*)d_in[14]; const float* b31 = (const float*)d_in[15];
    const float* w32 = (const float*)d_in[16]; const float* b32 = (const float*)d_in[17];
    const float* w33 = (const float*)d_in[18]; const float* b33 = (const float*)d_in[19];
    const float* h1w = (const float*)d_in[20]; const float* h1b = (const float*)d_in[21];
    const float* h2w = (const float*)d_in[22]; const float* h2b = (const float*)d_in[23];
    float* out = (float*)d_out;

    char* ws = (char*)d_ws;
    size_t off = 0;
    float* msum = (float*)(ws + off); off += (size_t)NBATCH*HW*4;            // 2 MB
    float* xo   = (float*)(ws + off); off += (size_t)NBATCH*384*4;           // 48 KB
    unsigned short* wp  = (unsigned short*)(ws + off); off += (size_t)WPREP_TOTAL*2;
    off = (off + 255) & ~(size_t)255;
    unsigned short* X2b = (unsigned short*)(ws + off); off += (size_t)NBATCH*32*HW*2;  // 33.5 MB
    off = (off + 255) & ~(size_t)255;

    int bc = 32;
    while (bc > 1 && off + 4ull*(size_t)bc*CCH*HW*2 > ws_size) bc >>= 1;
    size_t bufb = (size_t)bc*CCH*HW*2;
    unsigned short* bufA = (unsigned short*)(ws + off);
    unsigned short* bufB = (unsigned short*)(ws + off + bufb);
    unsigned short* bufP = (unsigned short*)(ws + off + 2*bufb);
    unsigned short* bufX = (unsigned short*)(ws + off + 3*bufb);

    const unsigned short* Wab1 = wp + 0;
    const unsigned short* Wc1  = wp + 16384;
    const unsigned short* Wab2 = wp + 57344;
    const unsigned short* Wc2  = wp + 122880;
    const unsigned short* Wab3 = wp + 188416;
    const unsigned short* Wc3  = wp + 253952;

    k_prep<<<(WPREP_TOTAL+255)/256, 256, 0, stream>>>(w11,w12,w13,w21,w22,w23,w31,w32,w33, wp);
    k_xprep<<<(NBATCH*16*HW)/256, 256, 0, stream>>>(X2, X2b);
    k_msum<<<(NBATCH*HW)/256, 256, 0, stream>>>(M, msum);
    hipMemsetAsync(xo, 0, (size_t)NBATCH*384*4, stream);

    for(int b0 = 0; b0 < NBATCH; b0 += bc){
        dim3 gab(HW/128, bc);
        dim3 gcc(HW/256, bc);
        dim3 gmat(bc*CCH);
        // ---- block 1
        k_cab<1,32,true  ><<<gab, 256, 0, stream>>>(Wab1, X2b,  b11, b12, msum, bufA, bufB, b0);
        k_bmm<<<gmat, 256, 0, stream>>>(bufA, bufB, msum, bufP, b0);
        k_cc <4,1,32,true ><<<gcc, 256, 0, stream>>>(Wc1, bufP, X2b,  b13, msum, M, bufX, xo, b0, 0);
        // ---- block 2
        k_cab<4,128,false><<<gab, 256, 0, stream>>>(Wab2, bufX, b21, b22, msum, bufA, bufB, b0);
        k_bmm<<<gmat, 256, 0, stream>>>(bufA, bufB, msum, bufP, b0);
        k_cc <4,4,128,false><<<gcc, 256, 0, stream>>>(Wc2, bufP, bufX, b23, msum, M, bufA, xo, b0, 128);
        // ---- block 3
        k_cab<4,128,false><<<gab, 256, 0, stream>>>(Wab3, bufA, b31, b32, msum, bufB, bufP, b0);
        k_bmm<<<gmat, 256, 0, stream>>>(bufB, bufP, msum, bufX, b0);
        k_cc <4,4,128,false><<<gcc, 256, 0, stream>>>(Wc3, bufX, bufA, b33, msum, M, bufB, xo, b0, 256);
    }
    k_head<<<1, 1024, 0, stream>>>(xo, h1w, h1b, h2w, h2b, out);
}